// Round 6
// baseline (126.693 us; speedup 1.0000x reference)
//
#include <hip/hip_runtime.h>

// ---- types ----
typedef __bf16 bf8_t  __attribute__((ext_vector_type(8)));   // 8 x bf16 = 4 VGPR (MFMA A/B frag)
typedef float  f4_t   __attribute__((ext_vector_type(4)));   // MFMA C/D frag
typedef unsigned short us4_t __attribute__((ext_vector_type(4)));

#define N_ROWS 4096
#define D_K    1024
#define TEMP_INV 20.0f   // 1 / 0.05  (folded into x-normalization)

// fp32 -> bf16, round-to-nearest-even (no NaN in this problem)
__device__ __forceinline__ unsigned short f2bf(float f) {
    unsigned int u = __builtin_bit_cast(unsigned int, f);
    u += 0x7fffu + ((u >> 16) & 1u);
    return (unsigned short)(u >> 16);
}

// async global->LDS, 16B per lane. LDS dest must be wave-uniform base + lane*16.
__device__ __forceinline__ void gl_lds16(const __bf16* g, __bf16* l) {
    __builtin_amdgcn_global_load_lds(
        (const __attribute__((address_space(1))) unsigned int*)g,
        (__attribute__((address_space(3))) unsigned int*)l,
        16, 0, 0);
}

// ---------------- fused row normalize for both inputs: v / max(||v||, eps), fp32 -> bf16 ----
// blocks [0,4096) -> x (scaled by 1/TEMP), [4096,8192) -> y. One block per row of 1024 floats.
__global__ __launch_bounds__(256) void norm_rows_kernel(
    const float* __restrict__ x, const float* __restrict__ y,
    unsigned short* __restrict__ xb, unsigned short* __restrict__ yb)
{
    const int b   = blockIdx.x;
    const int row = b & (N_ROWS - 1);
    const bool isx = (b < N_ROWS);
    const float* in     = isx ? x  : y;
    unsigned short* out = isx ? xb : yb;
    const float post    = isx ? TEMP_INV : 1.0f;
    const int t = threadIdx.x;
    const float4* ip = (const float4*)(in + (size_t)row * D_K);
    float4 v = ip[t];
    float ss = v.x*v.x + v.y*v.y + v.z*v.z + v.w*v.w;
    #pragma unroll
    for (int off = 32; off > 0; off >>= 1)
        ss += __shfl_down(ss, off, 64);
    __shared__ float red[4];
    if ((t & 63) == 0) red[t >> 6] = ss;
    __syncthreads();
    float tot   = red[0] + red[1] + red[2] + red[3];
    float scale = post / fmaxf(sqrtf(tot), 1e-8f);
    us4_t o;
    o.x = f2bf(v.x * scale);
    o.y = f2bf(v.y * scale);
    o.z = f2bf(v.z * scale);
    o.w = f2bf(v.w * scale);
    *(us4_t*)(out + (size_t)row * D_K + t * 4) = o;
}

// ---------------- C = A . B^T, A,B bf16 [4096][1024], C fp32 [4096][4096] ----------------
// (1/TEMP pre-folded into A.)
// R6: R2's proven 128x128 / 4-wave / 4x4x(16x16x32) structure, but BK=32 with DOUBLE-BUFFERED
// LDS and ONE barrier per k-iter. Prefetch for iter k+1 is issued immediately AFTER the barrier
// of iter k, so at barrier k+1 the drained loads have had a full compute phase in flight ->
// the vmcnt(0) drain (the measured ~50% idle) becomes near-free.
// Buffer safety (single barrier): ds_reads of iter k-1 are lgkmcnt-drained before any wave
// passes barrier k; stage(k+1) into the buffer iter k-1 read from is issued only after that.
// LDS XOR swizzle for BK=32: LDS slot s of row r holds global 8-elem k-group s ^ (r&3)
// (applied on the GLOBAL source address; LDS dest of global_load_lds is fixed base+lane*16).
// Fragment read slot = quad ^ (l15&3): 16 banks x 2-way per b128 phase -> free (m136).
__global__ __launch_bounds__(256, 4) void cosim_gemm_kernel(
    const unsigned short* __restrict__ Aus,
    const unsigned short* __restrict__ Bus,
    float* __restrict__ C)
{
    const __bf16* A = (const __bf16*)Aus;
    const __bf16* B = (const __bf16*)Bus;

    __shared__ __align__(16) __bf16 As0[128 * 32], Bs0[128 * 32];   // 8 KB each
    __shared__ __align__(16) __bf16 As1[128 * 32], Bs1[128 * 32];   // 32 KB total

    const int t    = threadIdx.x;
    const int lane = t & 63;
    const int wid  = t >> 6;
    const int wm   = wid >> 1;   // 0..1  (M half)
    const int wn   = wid & 1;    // 0..1  (N half)
    const int bm   = blockIdx.x;
    const int bn   = blockIdx.y;

    // staging: thread t -> (row sr, slot t&3), global group sg = (t&3)^(sr&3); 2 issues/matrix
    const int sr = t >> 2;                     // 0..63
    const int sg = (t & 3) ^ (sr & 3);         // swizzled source col-group
    const __bf16* ag = A + (size_t)(bm * 128 + sr) * D_K + sg * 8;
    const __bf16* bg = B + (size_t)(bn * 128 + sr) * D_K + sg * 8;
    const int toff = t * 8;                    // LDS elem offset, issue 0 (issue 1: +2048)

    // fragment read offsets (elements) into a 128x32 buffer
    const int l15  = lane & 15;
    const int quad = lane >> 4;
    const int slot = (quad ^ (l15 & 3)) * 8;
    int aoff[4], boff[4];
    #pragma unroll
    for (int mi = 0; mi < 4; mi++) aoff[mi] = (wm * 64 + mi * 16 + l15) * 32 + slot;
    #pragma unroll
    for (int ni = 0; ni < 4; ni++) boff[ni] = (wn * 64 + ni * 16 + l15) * 32 + slot;

    f4_t acc[4][4];
    #pragma unroll
    for (int mi = 0; mi < 4; mi++)
        #pragma unroll
        for (int ni = 0; ni < 4; ni++) {
            acc[mi][ni][0] = 0.f; acc[mi][ni][1] = 0.f;
            acc[mi][ni][2] = 0.f; acc[mi][ni][3] = 0.f;
        }

#define STAGE(k0, aD, bD) do {                                          \
        gl_lds16(ag + (k0),                      (aD) + toff);          \
        gl_lds16(ag + 64 * (size_t)D_K + (k0),   (aD) + toff + 2048);   \
        gl_lds16(bg + (k0),                      (bD) + toff);          \
        gl_lds16(bg + 64 * (size_t)D_K + (k0),   (bD) + toff + 2048);   \
    } while (0)

#define COMPUTE(aS, bS) do {                                            \
        bf8_t af[4], bfr[4];                                            \
        _Pragma("unroll")                                               \
        for (int mi = 0; mi < 4; mi++) af[mi]  = *(const bf8_t*)((aS) + aoff[mi]); \
        _Pragma("unroll")                                               \
        for (int ni = 0; ni < 4; ni++) bfr[ni] = *(const bf8_t*)((bS) + boff[ni]); \
        _Pragma("unroll")                                               \
        for (int mi = 0; mi < 4; mi++)                                  \
            _Pragma("unroll")                                           \
            for (int ni = 0; ni < 4; ni++)                              \
                acc[mi][ni] = __builtin_amdgcn_mfma_f32_16x16x32_bf16(  \
                    af[mi], bfr[ni], acc[mi][ni], 0, 0, 0);             \
    } while (0)

    STAGE(0, As0, Bs0);                         // prologue: iter 0 into buf0

    for (int it = 0; it < 32; it += 2) {
        __syncthreads();                        // drains stage(it) — in flight since iter it-1
        STAGE((it + 1) * 32, As1, Bs1);         // prefetch it+1 (always valid: it+1 <= 31)
        COMPUTE(As0, Bs0);
        __syncthreads();                        // drains stage(it+1) — in flight during COMPUTE
        if (it < 30) STAGE((it + 2) * 32, As0, Bs0);
        COMPUTE(As1, Bs1);
    }
#undef STAGE
#undef COMPUTE

    // epilogue: C/D layout col = lane&15, row = (lane>>4)*4 + reg  [m89/m91 verified]
    #pragma unroll
    for (int mi = 0; mi < 4; mi++) {
        #pragma unroll
        for (int ni = 0; ni < 4; ni++) {
            const int row = bm * 128 + wm * 64 + mi * 16 + quad * 4;
            const int col = bn * 128 + wn * 64 + ni * 16 + l15;
            #pragma unroll
            for (int r = 0; r < 4; r++)
                C[(size_t)(row + r) * N_ROWS + col] = acc[mi][ni][r];
        }
    }
}

extern "C" void kernel_launch(void* const* d_in, const int* in_sizes, int n_in,
                              void* d_out, int out_size, void* d_ws, size_t ws_size,
                              hipStream_t stream)
{
    const float* x = (const float*)d_in[0];
    const float* y = (const float*)d_in[1];
    float* out = (float*)d_out;

    unsigned short* xb = (unsigned short*)d_ws;                 // 8 MB
    unsigned short* yb = xb + (size_t)N_ROWS * D_K;             // 8 MB

    norm_rows_kernel<<<2 * N_ROWS, 256, 0, stream>>>(x, y, xb, yb);

    dim3 grid(N_ROWS / 128, N_ROWS / 128);
    cosim_gemm_kernel<<<grid, 256, 0, stream>>>(xb, yb, out);
}